// Round 7
// baseline (74.713 us; speedup 1.0000x reference)
//
#include <hip/hip_runtime.h>
#include <hip/hip_bf16.h>

// Quanv1D: out[i] = bias[i] + sum_d s_i(d) |(W' m_p)_d|^2
// GEMM [65480 x 256] x [256 x 512] (split-bf16, 3 MFMA per product)
// + sign-GEMM (+/-1 B built in regs, probs hi+lo).
// R7 = R5's source (R2 phase logic, 32-patch tile, LDS 34.8 KB) with ONE
// change: __launch_bounds__(256,4) -> (256,2). R3/R4/R5 all failed with
// minwaves=4 (VGPR cap 128 => AGPR spill juggling, suspected miscompile);
// R2/R6 passed with minwaves=2. Single-bit discriminating experiment.

#define TOTAL_PATCHES 65480
#define LOUT 8185
#define LBATCH 8192

typedef short bf16x8 __attribute__((ext_vector_type(8)));
typedef float f32x4 __attribute__((ext_vector_type(4)));

static __device__ __forceinline__ unsigned short f2bf(float f) {
  union { float f; unsigned u; } v; v.f = f;
  unsigned r = v.u + 0x7FFFu + ((v.u >> 16) & 1u);
  return (unsigned short)(r >> 16);
}
static __device__ __forceinline__ float bf2f(unsigned short h) {
  union { unsigned u; float f; } v; v.u = ((unsigned)h) << 16;
  return v.f;
}

// ---------------- Kernel 1: build W' (hi/lo) in MFMA-fragment layout -----
// flat_short_idx = ((kc*32 + nt)*64 + lane)*8 + j
// k = kc*32 + (lane>>4)*8 + j (K index), n = nt*16 + (lane&15) (col).
__global__ __launch_bounds__(64) void build_unitary(const float* __restrict__ w,
                                                    unsigned short* __restrict__ wfH,
                                                    unsigned short* __restrict__ wfL) {
  __shared__ float re[256], im[256];
  const int k = blockIdx.x;
  const int t = threadIdx.x;
  for (int idx = t; idx < 256; idx += 64) { re[idx] = 0.f; im[idx] = 0.f; }
  __syncthreads();
  if (t == 0) re[k] = 1.f;
  __syncthreads();
  for (int l = 0; l < 2; ++l) {
    for (int wi = 0; wi < 8; ++wi) {
      float phi = w[(l * 8 + wi) * 3 + 0];
      float th  = w[(l * 8 + wi) * 3 + 1];
      float om  = w[(l * 8 + wi) * 3 + 2];
      float ch = cosf(0.5f * th), sh = sinf(0.5f * th);
      float aa = 0.5f * (phi + om), bb = 0.5f * (phi - om);
      float ca = cosf(aa), sa = sinf(aa), cb = cosf(bb), sb = sinf(bb);
      float m00r = ch * ca, m00i = -ch * sa;
      float m01r = -sh * cb, m01i = -sh * sb;
      float m10r = sh * cb,  m10i = -sh * sb;
      float m11r = ch * ca,  m11i = ch * sa;
      int pos = 7 - wi;
      int mask = 1 << pos;
      int lowm = mask - 1;
      for (int pp = t; pp < 128; pp += 64) {
        int d0 = ((pp & ~lowm) << 1) | (pp & lowm);
        int d1 = d0 | mask;
        float a0r = re[d0], a0i = im[d0], a1r = re[d1], a1i = im[d1];
        re[d0] = m00r * a0r - m00i * a0i + m01r * a1r - m01i * a1i;
        im[d0] = m00r * a0i + m00i * a0r + m01r * a1i + m01i * a1r;
        re[d1] = m10r * a0r - m10i * a0i + m11r * a1r - m11i * a1i;
        im[d1] = m10r * a0i + m10i * a0r + m11r * a1i + m11i * a1r;
      }
      __syncthreads();
    }
    int r = (l % 7) + 1;
    for (int wi = 0; wi < 8; ++wi) {
      int c = wi, tg = (wi + r) & 7;
      int pc = 7 - c, pt = 7 - tg;
      int p1 = pc > pt ? pc : pt, p0 = pc < pt ? pc : pt;
      int lm0 = (1 << p0) - 1;
      int v2 = ((t & ~lm0) << 1) | (t & lm0);
      int lm1 = (1 << p1) - 1;
      int db = ((v2 & ~lm1) << 1) | (v2 & lm1);
      int d0 = db | (1 << pc);
      int d1 = d0 | (1 << pt);
      float tr = re[d0], ti = im[d0];
      re[d0] = re[d1]; im[d0] = im[d1];
      re[d1] = tr;     im[d1] = ti;
      __syncthreads();
    }
  }
  int pop = __popc(k) & 3;
  for (int idx = t; idx < 512; idx += 64) {
    int n = idx;
    int d = n & 255;
    float vr = re[d], vi = im[d];
    float pr, qi;
    if (pop == 0)      { pr =  vr; qi =  vi; }
    else if (pop == 1) { pr =  vi; qi = -vr; }
    else if (pop == 2) { pr = -vr; qi = -vi; }
    else               { pr = -vi; qi =  vr; }
    float val = (n < 256) ? pr : qi;
    int off = (((k >> 5) * 32 + (n >> 4)) * 64 + ((k >> 3) & 3) * 16 + (n & 15)) * 8 + (k & 7);
    unsigned short h = f2bf(val);
    wfH[off] = h;
    wfL[off] = f2bf(val - bf2f(h));
  }
}

// ---------------- Kernel 2: per-element angle tables ---------------------
__global__ __launch_bounds__(256) void prep_cs(const float* __restrict__ x,
                                               float* __restrict__ cs,
                                               float* __restrict__ sn) {
  int e = blockIdx.x * 256 + threadIdx.x;
  float t = tanhf(x[e]);
  float ang = 1.57079632679489662f * t;
  float s, c;
  __sincosf(ang, &s, &c);
  cs[e] = c;
  sn[e] = s;
}

// ---------------- Kernel 3: m-gen + split GEMM + epilogue (R2 maps, 32-tile) ---
__global__ __launch_bounds__(256, 2) void quanv_main(
    const float* __restrict__ cs, const float* __restrict__ sn,
    const bf16x8* __restrict__ wfH, const bf16x8* __restrict__ wfL,
    const float* __restrict__ bias, float* __restrict__ out) {
  __shared__ __align__(16) unsigned short AH[32 * 264];  // A hi; reused for probs hi
  __shared__ __align__(16) unsigned short AL[32 * 264];  // A lo; reused for probs lo
  __shared__ float esm[256];
  const int tid = threadIdx.x;
  const int lane = tid & 63;
  const int wave = tid >> 6;
  const int pbase = blockIdx.x * 32;

  // --- phase 1: build m-tile [32 x 256] hi/lo bf16 into LDS (R2 per-thread code) ---
  if (tid < 128) {
    int pl = tid >> 2, q = tid & 3;    // pl 0..31, q: k-quadrant (64 k each)
    int patch = pbase + pl;
    if (patch > TOTAL_PATCHES - 1) patch = TOTAL_PATCHES - 1;
    int b = patch / LOUT;
    int l = patch - b * LOUT;
    int base = b * LBATCH + l;
    float fc[8], fs[8];
#pragma unroll
    for (int wq = 0; wq < 8; ++wq) { fc[wq] = cs[base + wq]; fs[wq] = sn[base + wq]; }
    float arr[64];
    arr[0] = ((q & 2) ? fs[0] : fc[0]) * ((q & 1) ? fs[1] : fc[1]);
#pragma unroll
    for (int lev = 0; lev < 6; ++lev) {
      int wq = 7 - lev;
      int sz = 1 << lev;
#pragma unroll
      for (int j = 0; j < 64; ++j) {
        if (j < sz) {
          float a = arr[j];
          arr[sz + j] = a * fs[wq];
          arr[j] = a * fc[wq];
        }
      }
    }
#pragma unroll
    for (int j8 = 0; j8 < 8; ++j8) {
      bf16x8 vH, vL;
#pragma unroll
      for (int jj = 0; jj < 8; ++jj) {
        float a = arr[j8 * 8 + jj];
        unsigned short h = f2bf(a);
        vH[jj] = (short)h;
        vL[jj] = (short)f2bf(a - bf2f(h));
      }
      *(bf16x8*)&AH[pl * 264 + q * 64 + j8 * 8] = vH;
      *(bf16x8*)&AL[pl * 264 + q * 64 + j8 * 8] = vL;
    }
  }
  __syncthreads();

  // --- phase 2: split GEMM; wave covers nt {4w..4w+3} (Re) + {16+4w..} (Im) ---
  f32x4 acc[2][8];
#pragma unroll
  for (int i = 0; i < 2; ++i)
#pragma unroll
    for (int j = 0; j < 8; ++j) acc[i][j] = (f32x4){0.f, 0.f, 0.f, 0.f};

#pragma unroll
  for (int kc = 0; kc < 8; ++kc) {
    bf16x8 afH[2], afL[2];
#pragma unroll
    for (int mt = 0; mt < 2; ++mt) {
      int row = mt * 16 + (lane & 15);
      int col = kc * 32 + (lane >> 4) * 8;
      afH[mt] = *(const bf16x8*)&AH[row * 264 + col];
      afL[mt] = *(const bf16x8*)&AL[row * 264 + col];
    }
#pragma unroll
    for (int t8 = 0; t8 < 8; ++t8) {
      int nt = (t8 < 4) ? (wave * 4 + t8) : (16 + wave * 4 + t8 - 4);
      bf16x8 bH = wfH[(kc * 32 + nt) * 64 + lane];
      bf16x8 bL = wfL[(kc * 32 + nt) * 64 + lane];
#pragma unroll
      for (int mt = 0; mt < 2; ++mt) {
        acc[mt][t8] = __builtin_amdgcn_mfma_f32_16x16x32_bf16(afH[mt], bH, acc[mt][t8], 0, 0, 0);
        acc[mt][t8] = __builtin_amdgcn_mfma_f32_16x16x32_bf16(afL[mt], bH, acc[mt][t8], 0, 0, 0);
        acc[mt][t8] = __builtin_amdgcn_mfma_f32_16x16x32_bf16(afH[mt], bL, acc[mt][t8], 0, 0, 0);
      }
    }
  }

  __syncthreads();
  // --- phase 3: probs p = re^2+im^2, hi/lo bf16 -> [32][264] (alias A) ---
#pragma unroll
  for (int mt = 0; mt < 2; ++mt)
#pragma unroll
    for (int t4 = 0; t4 < 4; ++t4)
#pragma unroll
      for (int r = 0; r < 4; ++r) {
        float vr = acc[mt][t4][r], vi = acc[mt][t4 + 4][r];
        float p = vr * vr + vi * vi;
        int patch_l = mt * 16 + (lane >> 4) * 4 + r;
        int d = (wave * 4 + t4) * 16 + (lane & 15);
        unsigned short h = f2bf(p);
        AH[patch_l * 264 + d] = h;
        AL[patch_l * 264 + d] = f2bf(p - bf2f(h));
      }
  __syncthreads();

  // --- phase 4: sign-GEMM (waves 0..1) over hi+lo probs ---
  if (wave < 2) {
    f32x4 e4 = {0.f, 0.f, 0.f, 0.f};
    int io = lane & 15;
    int plr = wave * 16 + (lane & 15);
    int hi4 = lane >> 4;
#pragma unroll
    for (int kc2 = 0; kc2 < 8; ++kc2) {
      int k0 = kc2 * 32 + hi4 * 8;
      bf16x8 aH = *(const bf16x8*)&AH[plr * 264 + k0];
      bf16x8 aL = *(const bf16x8*)&AL[plr * 264 + k0];
      bf16x8 b2;
#pragma unroll
      for (int bb = 0; bb < 8; ++bb) {
        unsigned short sv = 0;
        if (io < 8) sv = (((k0 + bb) >> (7 - io)) & 1) ? 0xBF80u : 0x3F80u;
        b2[bb] = (short)sv;
      }
      e4 = __builtin_amdgcn_mfma_f32_16x16x32_bf16(aH, b2, e4, 0, 0, 0);
      e4 = __builtin_amdgcn_mfma_f32_16x16x32_bf16(aL, b2, e4, 0, 0, 0);
    }
    if (io < 8) {
      float bv = bias[io];
#pragma unroll
      for (int r = 0; r < 4; ++r)
        esm[io * 32 + (wave * 16 + hi4 * 4 + r)] = e4[r] + bv;
    }
  }
  __syncthreads();

  // --- phase 5: coalesced transposed store out[b][i][l] ---
  {
    int io2 = tid >> 5, pl2 = tid & 31;
    int patch = pbase + pl2;
    if (patch < TOTAL_PATCHES) {
      int b = patch / LOUT;
      int l = patch - b * LOUT;
      out[(b * 8 + io2) * LOUT + l] = esm[io2 * 32 + pl2];
    }
  }
}

extern "C" void kernel_launch(void* const* d_in, const int* in_sizes, int n_in,
                              void* d_out, int out_size, void* d_ws, size_t ws_size,
                              hipStream_t stream) {
  const float* x = (const float*)d_in[0];
  const float* w = (const float*)d_in[1];
  const float* bias = (const float*)d_in[2];
  float* out = (float*)d_out;
  char* ws = (char*)d_ws;
  unsigned short* wfH = (unsigned short*)ws;            // 262144 B
  unsigned short* wfL = (unsigned short*)(ws + 262144); // 262144 B
  float* cs = (float*)(ws + 524288);                    // 262144 B
  float* sn = (float*)(ws + 786432);                    // 262144 B

  build_unitary<<<256, 64, 0, stream>>>(w, wfH, wfL);
  prep_cs<<<256, 256, 0, stream>>>(x, cs, sn);
  quanv_main<<<2047, 256, 0, stream>>>(cs, sn, (const bf16x8*)wfH, (const bf16x8*)wfL, bias, out);
}

// Round 8
// 64.589 us; speedup vs baseline: 1.1568x; 1.1568x over previous
//
#include <hip/hip_runtime.h>
#include <hip/hip_bf16.h>

// Quanv1D: out[i] = bias[i] + sum_d s_i(d) |(W' m_p)_d|^2
// R8 = R7 (passing, 32-patch tile, launch_bounds(256,2) -- NEVER 4, that
// miscompiles) with the GEMM moved bf16-3-term -> fp16-2-term:
//   A = fp16 hi+lo split (2^-22 rel), B = single fp16 (2^-12 rel)
//   acc = AH*B + AL*B     (2 MFMA per product, B bytes halved)
// Probs staging + sign-GEMM also fp16 hi/lo. Thread maps identical to R7.

#define TOTAL_PATCHES 65480
#define LOUT 8185
#define LBATCH 8192

typedef _Float16 f16x8 __attribute__((ext_vector_type(8)));
typedef float f32x4 __attribute__((ext_vector_type(4)));

static __device__ __forceinline__ unsigned short f2h_bits(float f) {
  union { _Float16 h; unsigned short u; } v;
  v.h = (_Float16)f;
  return v.u;
}

// ---------------- Kernel 1: build W' (single fp16) in MFMA-fragment layout -----
// flat_short_idx = ((kc*32 + nt)*64 + lane)*8 + j
// k = kc*32 + (lane>>4)*8 + j (K index), n = nt*16 + (lane&15) (col).
__global__ __launch_bounds__(64) void build_unitary(const float* __restrict__ w,
                                                    unsigned short* __restrict__ wf16) {
  __shared__ float re[256], im[256];
  const int k = blockIdx.x;
  const int t = threadIdx.x;
  for (int idx = t; idx < 256; idx += 64) { re[idx] = 0.f; im[idx] = 0.f; }
  __syncthreads();
  if (t == 0) re[k] = 1.f;
  __syncthreads();
  for (int l = 0; l < 2; ++l) {
    for (int wi = 0; wi < 8; ++wi) {
      float phi = w[(l * 8 + wi) * 3 + 0];
      float th  = w[(l * 8 + wi) * 3 + 1];
      float om  = w[(l * 8 + wi) * 3 + 2];
      float ch = cosf(0.5f * th), sh = sinf(0.5f * th);
      float aa = 0.5f * (phi + om), bb = 0.5f * (phi - om);
      float ca = cosf(aa), sa = sinf(aa), cb = cosf(bb), sb = sinf(bb);
      float m00r = ch * ca, m00i = -ch * sa;
      float m01r = -sh * cb, m01i = -sh * sb;
      float m10r = sh * cb,  m10i = -sh * sb;
      float m11r = ch * ca,  m11i = ch * sa;
      int pos = 7 - wi;
      int mask = 1 << pos;
      int lowm = mask - 1;
      for (int pp = t; pp < 128; pp += 64) {
        int d0 = ((pp & ~lowm) << 1) | (pp & lowm);
        int d1 = d0 | mask;
        float a0r = re[d0], a0i = im[d0], a1r = re[d1], a1i = im[d1];
        re[d0] = m00r * a0r - m00i * a0i + m01r * a1r - m01i * a1i;
        im[d0] = m00r * a0i + m00i * a0r + m01r * a1i + m01i * a1r;
        re[d1] = m10r * a0r - m10i * a0i + m11r * a1r - m11i * a1i;
        im[d1] = m10r * a0i + m10i * a0r + m11r * a1i + m11i * a1r;
      }
      __syncthreads();
    }
    int r = (l % 7) + 1;
    for (int wi = 0; wi < 8; ++wi) {
      int c = wi, tg = (wi + r) & 7;
      int pc = 7 - c, pt = 7 - tg;
      int p1 = pc > pt ? pc : pt, p0 = pc < pt ? pc : pt;
      int lm0 = (1 << p0) - 1;
      int v2 = ((t & ~lm0) << 1) | (t & lm0);
      int lm1 = (1 << p1) - 1;
      int db = ((v2 & ~lm1) << 1) | (v2 & lm1);
      int d0 = db | (1 << pc);
      int d1 = d0 | (1 << pt);
      float tr = re[d0], ti = im[d0];
      re[d0] = re[d1]; im[d0] = im[d1];
      re[d1] = tr;     im[d1] = ti;
      __syncthreads();
    }
  }
  int pop = __popc(k) & 3;
  for (int idx = t; idx < 512; idx += 64) {
    int n = idx;
    int d = n & 255;
    float vr = re[d], vi = im[d];
    float pr, qi;
    if (pop == 0)      { pr =  vr; qi =  vi; }
    else if (pop == 1) { pr =  vi; qi = -vr; }
    else if (pop == 2) { pr = -vr; qi = -vi; }
    else               { pr = -vi; qi =  vr; }
    float val = (n < 256) ? pr : qi;
    int off = (((k >> 5) * 32 + (n >> 4)) * 64 + ((k >> 3) & 3) * 16 + (n & 15)) * 8 + (k & 7);
    wf16[off] = f2h_bits(val);
  }
}

// ---------------- Kernel 2: per-element angle tables ---------------------
__global__ __launch_bounds__(256) void prep_cs(const float* __restrict__ x,
                                               float* __restrict__ cs,
                                               float* __restrict__ sn) {
  int e = blockIdx.x * 256 + threadIdx.x;
  float t = tanhf(x[e]);
  float ang = 1.57079632679489662f * t;
  float s, c;
  __sincosf(ang, &s, &c);
  cs[e] = c;
  sn[e] = s;
}

// ---------------- Kernel 3: m-gen + fp16 GEMM + epilogue (R7 maps) -------
__global__ __launch_bounds__(256, 2) void quanv_main(
    const float* __restrict__ cs, const float* __restrict__ sn,
    const f16x8* __restrict__ wf, const float* __restrict__ bias,
    float* __restrict__ out) {
  __shared__ __align__(16) unsigned short AH[32 * 264];  // A hi; reused for probs hi
  __shared__ __align__(16) unsigned short AL[32 * 264];  // A lo; reused for probs lo
  __shared__ float esm[256];
  const int tid = threadIdx.x;
  const int lane = tid & 63;
  const int wave = tid >> 6;
  const int pbase = blockIdx.x * 32;

  // --- phase 1: build m-tile [32 x 256] hi/lo fp16 into LDS ---
  if (tid < 128) {
    int pl = tid >> 2, q = tid & 3;    // pl 0..31, q: k-quadrant (64 k each)
    int patch = pbase + pl;
    if (patch > TOTAL_PATCHES - 1) patch = TOTAL_PATCHES - 1;
    int b = patch / LOUT;
    int l = patch - b * LOUT;
    int base = b * LBATCH + l;
    float fc[8], fs[8];
#pragma unroll
    for (int wq = 0; wq < 8; ++wq) { fc[wq] = cs[base + wq]; fs[wq] = sn[base + wq]; }
    float arr[64];
    arr[0] = ((q & 2) ? fs[0] : fc[0]) * ((q & 1) ? fs[1] : fc[1]);
#pragma unroll
    for (int lev = 0; lev < 6; ++lev) {
      int wq = 7 - lev;
      int sz = 1 << lev;
#pragma unroll
      for (int j = 0; j < 64; ++j) {
        if (j < sz) {
          float a = arr[j];
          arr[sz + j] = a * fs[wq];
          arr[j] = a * fc[wq];
        }
      }
    }
#pragma unroll
    for (int j8 = 0; j8 < 8; ++j8) {
      f16x8 vH, vL;
#pragma unroll
      for (int jj = 0; jj < 8; ++jj) {
        float a = arr[j8 * 8 + jj];
        _Float16 hh = (_Float16)a;
        vH[jj] = hh;
        vL[jj] = (_Float16)(a - (float)hh);
      }
      *(f16x8*)&AH[pl * 264 + q * 64 + j8 * 8] = vH;
      *(f16x8*)&AL[pl * 264 + q * 64 + j8 * 8] = vL;
    }
  }
  __syncthreads();

  // --- phase 2: fp16 GEMM: acc = AH*B + AL*B ---
  f32x4 acc[2][8];
#pragma unroll
  for (int i = 0; i < 2; ++i)
#pragma unroll
    for (int j = 0; j < 8; ++j) acc[i][j] = (f32x4){0.f, 0.f, 0.f, 0.f};

#pragma unroll
  for (int kc = 0; kc < 8; ++kc) {
    f16x8 afH[2], afL[2];
#pragma unroll
    for (int mt = 0; mt < 2; ++mt) {
      int row = mt * 16 + (lane & 15);
      int col = kc * 32 + (lane >> 4) * 8;
      afH[mt] = *(const f16x8*)&AH[row * 264 + col];
      afL[mt] = *(const f16x8*)&AL[row * 264 + col];
    }
#pragma unroll
    for (int t8 = 0; t8 < 8; ++t8) {
      int nt = (t8 < 4) ? (wave * 4 + t8) : (16 + wave * 4 + t8 - 4);
      f16x8 b = wf[(kc * 32 + nt) * 64 + lane];
#pragma unroll
      for (int mt = 0; mt < 2; ++mt) {
        acc[mt][t8] = __builtin_amdgcn_mfma_f32_16x16x32_f16(afH[mt], b, acc[mt][t8], 0, 0, 0);
        acc[mt][t8] = __builtin_amdgcn_mfma_f32_16x16x32_f16(afL[mt], b, acc[mt][t8], 0, 0, 0);
      }
    }
  }

  __syncthreads();
  // --- phase 3: probs p = re^2+im^2, hi/lo fp16 -> [32][264] (alias A) ---
#pragma unroll
  for (int mt = 0; mt < 2; ++mt)
#pragma unroll
    for (int t4 = 0; t4 < 4; ++t4)
#pragma unroll
      for (int r = 0; r < 4; ++r) {
        float vr = acc[mt][t4][r], vi = acc[mt][t4 + 4][r];
        float p = vr * vr + vi * vi;
        int patch_l = mt * 16 + (lane >> 4) * 4 + r;
        int d = (wave * 4 + t4) * 16 + (lane & 15);
        _Float16 hh = (_Float16)p;
        AH[patch_l * 264 + d] = f2h_bits(p);
        AL[patch_l * 264 + d] = f2h_bits(p - (float)hh);
      }
  __syncthreads();

  // --- phase 4: sign-GEMM (waves 0..1) over hi+lo fp16 probs ---
  if (wave < 2) {
    f32x4 e4 = {0.f, 0.f, 0.f, 0.f};
    int io = lane & 15;
    int plr = wave * 16 + (lane & 15);
    int hi4 = lane >> 4;
#pragma unroll
    for (int kc2 = 0; kc2 < 8; ++kc2) {
      int k0 = kc2 * 32 + hi4 * 8;
      f16x8 aH = *(const f16x8*)&AH[plr * 264 + k0];
      f16x8 aL = *(const f16x8*)&AL[plr * 264 + k0];
      f16x8 b2;
#pragma unroll
      for (int bb = 0; bb < 8; ++bb) {
        _Float16 sv = (_Float16)0.f;
        if (io < 8) sv = (((k0 + bb) >> (7 - io)) & 1) ? (_Float16)(-1.f) : (_Float16)(1.f);
        b2[bb] = sv;
      }
      e4 = __builtin_amdgcn_mfma_f32_16x16x32_f16(aH, b2, e4, 0, 0, 0);
      e4 = __builtin_amdgcn_mfma_f32_16x16x32_f16(aL, b2, e4, 0, 0, 0);
    }
    if (io < 8) {
      float bv = bias[io];
#pragma unroll
      for (int r = 0; r < 4; ++r)
        esm[io * 32 + (wave * 16 + hi4 * 4 + r)] = e4[r] + bv;
    }
  }
  __syncthreads();

  // --- phase 5: coalesced transposed store out[b][i][l] ---
  {
    int io2 = tid >> 5, pl2 = tid & 31;
    int patch = pbase + pl2;
    if (patch < TOTAL_PATCHES) {
      int b = patch / LOUT;
      int l = patch - b * LOUT;
      out[(b * 8 + io2) * LOUT + l] = esm[io2 * 32 + pl2];
    }
  }
}

extern "C" void kernel_launch(void* const* d_in, const int* in_sizes, int n_in,
                              void* d_out, int out_size, void* d_ws, size_t ws_size,
                              hipStream_t stream) {
  const float* x = (const float*)d_in[0];
  const float* w = (const float*)d_in[1];
  const float* bias = (const float*)d_in[2];
  float* out = (float*)d_out;
  char* ws = (char*)d_ws;
  unsigned short* wf16 = (unsigned short*)ws;           // 262144 B
  float* cs = (float*)(ws + 262144);                    // 262144 B
  float* sn = (float*)(ws + 524288);                    // 262144 B

  build_unitary<<<256, 64, 0, stream>>>(w, wf16);
  prep_cs<<<256, 256, 0, stream>>>(x, cs, sn);
  quanv_main<<<2047, 256, 0, stream>>>(cs, sn, (const f16x8*)wf16, bias, out);
}

// Round 9
// 60.350 us; speedup vs baseline: 1.2380x; 1.0702x over previous
//
#include <hip/hip_runtime.h>
#include <hip/hip_bf16.h>

// Quanv1D: out[i] = bias[i] + sum_d s_i(d) |(W' m_p)_d|^2
// R9 = R8 (fp16 2-term GEMM, 32-patch tile, launch_bounds(256,2) -- NEVER
// (,4), that miscompiles) with:
//  - A-tile in MFMA-fragment order, lane-sequential 16B => zero LDS bank
//    conflicts on phase-1 writes and phase-2 reads (was 8-way, 3.0M cyc)
//  - phase-1 m-gen spread over all 256 threads (was 128)
//  - build_unitary + prep_cs fused into one launch (prep_all)

#define TOTAL_PATCHES 65480
#define LOUT 8185
#define LBATCH 8192

typedef _Float16 f16x8 __attribute__((ext_vector_type(8)));
typedef float f32x4 __attribute__((ext_vector_type(4)));

static __device__ __forceinline__ unsigned short f2h_bits(float f) {
  union { _Float16 h; unsigned short u; } v;
  v.h = (_Float16)f;
  return v.u;
}

// ---------------- Kernel 1: fused W'-build (blocks 0..255) + angle tables ----
// W' layout: flat_short_idx = ((kc*32 + nt)*64 + lane)*8 + j
// k = kc*32 + (lane>>4)*8 + j (K index), n = nt*16 + (lane&15) (col).
__global__ __launch_bounds__(256) void prep_all(const float* __restrict__ x,
                                                const float* __restrict__ w,
                                                unsigned short* __restrict__ wf16,
                                                float* __restrict__ cs,
                                                float* __restrict__ sn) {
  if (blockIdx.x >= 256) {
    int e = (blockIdx.x - 256) * 256 + threadIdx.x;
    float t = tanhf(x[e]);
    float s, c;
    __sincosf(1.57079632679489662f * t, &s, &c);
    cs[e] = c;
    sn[e] = s;
    return;
  }
  __shared__ float re[256], im[256];
  const int k = blockIdx.x;
  const int t = threadIdx.x;
  re[t] = 0.f; im[t] = 0.f;
  __syncthreads();
  if (t == 0) re[k] = 1.f;
  __syncthreads();
  for (int l = 0; l < 2; ++l) {
    for (int wi = 0; wi < 8; ++wi) {
      float phi = w[(l * 8 + wi) * 3 + 0];
      float th  = w[(l * 8 + wi) * 3 + 1];
      float om  = w[(l * 8 + wi) * 3 + 2];
      float ch = cosf(0.5f * th), sh = sinf(0.5f * th);
      float aa = 0.5f * (phi + om), bb = 0.5f * (phi - om);
      float ca = cosf(aa), sa = sinf(aa), cb = cosf(bb), sb = sinf(bb);
      float m00r = ch * ca, m00i = -ch * sa;
      float m01r = -sh * cb, m01i = -sh * sb;
      float m10r = sh * cb,  m10i = -sh * sb;
      float m11r = ch * ca,  m11i = ch * sa;
      int pos = 7 - wi;
      int mask = 1 << pos;
      int lowm = mask - 1;
      if (t < 128) {
        int pp = t;
        int d0 = ((pp & ~lowm) << 1) | (pp & lowm);
        int d1 = d0 | mask;
        float a0r = re[d0], a0i = im[d0], a1r = re[d1], a1i = im[d1];
        re[d0] = m00r * a0r - m00i * a0i + m01r * a1r - m01i * a1i;
        im[d0] = m00r * a0i + m00i * a0r + m01r * a1i + m01i * a1r;
        re[d1] = m10r * a0r - m10i * a0i + m11r * a1r - m11i * a1i;
        im[d1] = m10r * a0i + m10i * a0r + m11r * a1i + m11i * a1r;
      }
      __syncthreads();
    }
    int r = (l % 7) + 1;
    for (int wi = 0; wi < 8; ++wi) {
      int c = wi, tg = (wi + r) & 7;
      int pc = 7 - c, pt = 7 - tg;
      int p1 = pc > pt ? pc : pt, p0 = pc < pt ? pc : pt;
      if (t < 64) {
        int lm0 = (1 << p0) - 1;
        int v2 = ((t & ~lm0) << 1) | (t & lm0);
        int lm1 = (1 << p1) - 1;
        int db = ((v2 & ~lm1) << 1) | (v2 & lm1);
        int d0 = db | (1 << pc);
        int d1 = d0 | (1 << pt);
        float tr = re[d0], ti = im[d0];
        re[d0] = re[d1]; im[d0] = im[d1];
        re[d1] = tr;     im[d1] = ti;
      }
      __syncthreads();
    }
  }
  int pop = __popc(k) & 3;
  for (int idx = t; idx < 512; idx += 256) {
    int n = idx;
    int d = n & 255;
    float vr = re[d], vi = im[d];
    float pr, qi;
    if (pop == 0)      { pr =  vr; qi =  vi; }
    else if (pop == 1) { pr =  vi; qi = -vr; }
    else if (pop == 2) { pr = -vr; qi = -vi; }
    else               { pr = -vi; qi =  vr; }
    float val = (n < 256) ? pr : qi;
    int off = (((k >> 5) * 32 + (n >> 4)) * 64 + ((k >> 3) & 3) * 16 + (n & 15)) * 8 + (k & 7);
    wf16[off] = f2h_bits(val);
  }
}

// ---------------- Kernel 2: m-gen + fp16 GEMM + epilogue -----------------
__global__ __launch_bounds__(256, 2) void quanv_main(
    const float* __restrict__ cs, const float* __restrict__ sn,
    const f16x8* __restrict__ wf, const float* __restrict__ bias,
    float* __restrict__ out) {
  __shared__ __align__(16) unsigned short R0[32 * 264];  // A-frag hi (8192 used) / probs hi [32][264]
  __shared__ __align__(16) unsigned short R1[32 * 264];  // A-frag lo / probs lo
  __shared__ float esm[256];
  const int tid = threadIdx.x;
  const int lane = tid & 63;
  const int wave = tid >> 6;
  const int pbase = blockIdx.x * 32;

  // --- phase 1: m-tile [32 x 256] hi/lo fp16, FRAGMENT order, all 256 thr ---
  // thread (pl=tid&31, q=tid>>5): patch pbase+pl, k-range q*32..q*32+31.
  // frag f = q*2 + (pl>>4); lane l' = (pl&15) + 16*khalf; elem j = k&7.
  // Wave-lane order == slot order => conflict-free ds_write_b128.
  {
    int pl = tid & 31, q = tid >> 5;
    int patch = pbase + pl;
    if (patch > TOTAL_PATCHES - 1) patch = TOTAL_PATCHES - 1;
    int b = patch / LOUT;
    int l = patch - b * LOUT;
    int base = b * LBATCH + l;
    float fc[8], fs[8];
#pragma unroll
    for (int wq = 0; wq < 8; ++wq) { fc[wq] = cs[base + wq]; fs[wq] = sn[base + wq]; }
    // k = q*32 + idx5; k bits 7..5 = q (wires 0..2); idx5 bit lev = wire 7-lev
    float arr[32];
    arr[0] = ((q & 4) ? fs[0] : fc[0]) * ((q & 2) ? fs[1] : fc[1]) * ((q & 1) ? fs[2] : fc[2]);
#pragma unroll
    for (int lev = 0; lev < 5; ++lev) {
      int wq = 7 - lev;
      int sz = 1 << lev;
#pragma unroll
      for (int j = 0; j < 32; ++j) {
        if (j < sz) {
          float a = arr[j];
          arr[sz + j] = a * fs[wq];
          arr[j] = a * fc[wq];
        }
      }
    }
    int fragbase = (q * 2 + (pl >> 4)) * 64 + (pl & 15);
#pragma unroll
    for (int khalf = 0; khalf < 4; ++khalf) {
      f16x8 vH, vL;
#pragma unroll
      for (int jj = 0; jj < 8; ++jj) {
        float a = arr[khalf * 8 + jj];
        _Float16 hh = (_Float16)a;
        vH[jj] = hh;
        vL[jj] = (_Float16)(a - (float)hh);
      }
      *(f16x8*)&R0[(fragbase + khalf * 16) * 8] = vH;
      *(f16x8*)&R1[(fragbase + khalf * 16) * 8] = vL;
    }
  }
  __syncthreads();

  // --- phase 2: fp16 GEMM: acc = AH*B + AL*B (frag-order A reads) ---
  f32x4 acc[2][8];
#pragma unroll
  for (int i = 0; i < 2; ++i)
#pragma unroll
    for (int j = 0; j < 8; ++j) acc[i][j] = (f32x4){0.f, 0.f, 0.f, 0.f};

#pragma unroll
  for (int kc = 0; kc < 8; ++kc) {
    f16x8 afH[2], afL[2];
#pragma unroll
    for (int mt = 0; mt < 2; ++mt) {
      afH[mt] = *(const f16x8*)&R0[((kc * 2 + mt) * 64 + lane) * 8];
      afL[mt] = *(const f16x8*)&R1[((kc * 2 + mt) * 64 + lane) * 8];
    }
#pragma unroll
    for (int t8 = 0; t8 < 8; ++t8) {
      int nt = (t8 < 4) ? (wave * 4 + t8) : (16 + wave * 4 + t8 - 4);
      f16x8 b = wf[(kc * 32 + nt) * 64 + lane];
#pragma unroll
      for (int mt = 0; mt < 2; ++mt) {
        acc[mt][t8] = __builtin_amdgcn_mfma_f32_16x16x32_f16(afH[mt], b, acc[mt][t8], 0, 0, 0);
        acc[mt][t8] = __builtin_amdgcn_mfma_f32_16x16x32_f16(afL[mt], b, acc[mt][t8], 0, 0, 0);
      }
    }
  }

  __syncthreads();
  // --- phase 3: probs p = re^2+im^2, hi/lo fp16 -> [32][264] (alias) ---
#pragma unroll
  for (int mt = 0; mt < 2; ++mt)
#pragma unroll
    for (int t4 = 0; t4 < 4; ++t4)
#pragma unroll
      for (int r = 0; r < 4; ++r) {
        float vr = acc[mt][t4][r], vi = acc[mt][t4 + 4][r];
        float p = vr * vr + vi * vi;
        int patch_l = mt * 16 + (lane >> 4) * 4 + r;
        int d = (wave * 4 + t4) * 16 + (lane & 15);
        _Float16 hh = (_Float16)p;
        R0[patch_l * 264 + d] = f2h_bits(p);
        R1[patch_l * 264 + d] = f2h_bits(p - (float)hh);
      }
  __syncthreads();

  // --- phase 4: sign-GEMM (waves 0..1) over hi+lo fp16 probs ---
  if (wave < 2) {
    f32x4 e4 = {0.f, 0.f, 0.f, 0.f};
    int io = lane & 15;
    int plr = wave * 16 + (lane & 15);
    int hi4 = lane >> 4;
#pragma unroll
    for (int kc2 = 0; kc2 < 8; ++kc2) {
      int k0 = kc2 * 32 + hi4 * 8;
      f16x8 aH = *(const f16x8*)&R0[plr * 264 + k0];
      f16x8 aL = *(const f16x8*)&R1[plr * 264 + k0];
      f16x8 b2;
#pragma unroll
      for (int bb = 0; bb < 8; ++bb) {
        _Float16 sv = (_Float16)0.f;
        if (io < 8) sv = (((k0 + bb) >> (7 - io)) & 1) ? (_Float16)(-1.f) : (_Float16)(1.f);
        b2[bb] = sv;
      }
      e4 = __builtin_amdgcn_mfma_f32_16x16x32_f16(aH, b2, e4, 0, 0, 0);
      e4 = __builtin_amdgcn_mfma_f32_16x16x32_f16(aL, b2, e4, 0, 0, 0);
    }
    if (io < 8) {
      float bv = bias[io];
#pragma unroll
      for (int r = 0; r < 4; ++r)
        esm[io * 32 + (wave * 16 + hi4 * 4 + r)] = e4[r] + bv;
    }
  }
  __syncthreads();

  // --- phase 5: coalesced transposed store out[b][i][l] ---
  {
    int io2 = tid >> 5, pl2 = tid & 31;
    int patch = pbase + pl2;
    if (patch < TOTAL_PATCHES) {
      int b = patch / LOUT;
      int l = patch - b * LOUT;
      out[(b * 8 + io2) * LOUT + l] = esm[io2 * 32 + pl2];
    }
  }
}

extern "C" void kernel_launch(void* const* d_in, const int* in_sizes, int n_in,
                              void* d_out, int out_size, void* d_ws, size_t ws_size,
                              hipStream_t stream) {
  const float* x = (const float*)d_in[0];
  const float* w = (const float*)d_in[1];
  const float* bias = (const float*)d_in[2];
  float* out = (float*)d_out;
  char* ws = (char*)d_ws;
  unsigned short* wf16 = (unsigned short*)ws;           // 262144 B
  float* cs = (float*)(ws + 262144);                    // 262144 B
  float* sn = (float*)(ws + 524288);                    // 262144 B

  prep_all<<<512, 256, 0, stream>>>(x, w, wf16, cs, sn);
  quanv_main<<<2047, 256, 0, stream>>>(cs, sn, (const f16x8*)wf16, bias, out);
}